// Round 5
// baseline (538.229 us; speedup 1.0000x reference)
//
#include <hip/hip_runtime.h>

// NearestNeighborTokenizer: ids = (min_c ||x - c||^2 <= 900) ? argmin_c : -1
// x: [8192, 512] fp32, codes: [16384, 512] fp32, out: [8192] int32
//
// fp16x3 MFMA GEMM: x,c scaled by 16, split into fp16 hi+lo planes,
// pre-swizzled in global memory into MFMA fragment order. dot =
// (hh + hl + lh)/256 in one fp32 acc. score = ||c||^2 - 2*dot.
//
// R10 == R9 resubmitted (round 4 bench was an infra failure: "container
// failed twice", no verdict/profile — same signature as round 1, which
// cleared on identical resubmission. Hang-audit: uniform barriers,
// disjoint table ownership, in-bounds LDS addressing, 136KiB < 160KiB.)
//
// R9: 32x32x16 MFMA shape. R5/R6/R8 post-mortem: three structures
// (monolithic counted-vmcnt, 4-phase+setprio, A-direct) all land at
// 354-372us = 59.5% of the f16 16x16 uarch ceiling (1955 TF) -- the
// structural efficiency of this schedule class (8-phase template tops
// at 62.6% of ITS ceiling). Schedule tuning is exhausted; raise the
// ceiling instead: v_mfma_f32_32x32x16_f16 runs at 2178 TF (+11.4%)
// and halves instruction count (48 vs 96 MFMA/wave-iter). Same FLOP,
// same staging bytes, same ds_read count. C layout (m74/m101):
// col=lane&31, row=(reg&3)+8*(reg>>2)+4*(lane>>5). A/B frag: lane&31 =
// m/n index, lane>>5 = k-half, 8 contiguous k per lane. Per-nt argmin
// reduces via shfl into a 4KB LDS running table (keeps regs <= 256 for
// 2 waves/SIMD).

#define NTOK   8192
#define NCODES 16384
#define DDIM   512
#define NCHUNK 8
#define CHUNK  2048
#define DIST_THR 900.0f

typedef unsigned short u16;
typedef _Float16 half8 __attribute__((ext_vector_type(8)));
typedef float    f32x4  __attribute__((ext_vector_type(4)));
typedef float    f32x16 __attribute__((ext_vector_type(16)));

// ---------------- kernel 1: merged prep -------------------------------------
// blocks [0,2048): convert+swizzle x -> xh/xl
// blocks [2048,6144): convert+swizzle codes -> ch/cl
// blocks [6144,10240): c2[c] = ||codes[c]||^2 (one wave per code)
//
// Swizzle for 32x32x16 fragments. Linear unit index c (8 halfs each):
//   L=c&63, f=(c>>6)&7, kit=(c>>9)&15, tile=c>>13 ; g=f>>1, ks=f&1
//   row = tile*128 + g*32 + (L&31) ; k = kit*32 + ks*16 + (L>>5)*8
// Each (tile,kit) is a contiguous 8KB block = 8 fragments x 1KB in
// exactly the MFMA operand order (lane L <-> row/col base+(L&31),
// k-half L>>5, 8 contiguous k).
__device__ __forceinline__ void conv_body(const float* __restrict__ src,
                                          u16* __restrict__ dh,
                                          u16* __restrict__ dl, int c) {
    int L = c & 63, f = (c >> 6) & 7, kit = (c >> 9) & 15;
    int tile = c >> 13;
    int g = f >> 1, ks = f & 1;
    int row = tile * 128 + g * 32 + (L & 31);
    int k = kit * 32 + ks * 16 + (L >> 5) * 8;
    const float* p = src + (size_t)row * DDIM + k;
    float4 v0 = *(const float4*)p;
    float4 v1 = *(const float4*)(p + 4);
    float vv[8] = {v0.x, v0.y, v0.z, v0.w, v1.x, v1.y, v1.z, v1.w};
    u16 hs[8], ls[8];
    #pragma unroll
    for (int j = 0; j < 8; ++j) {
        float sv = vv[j] * 16.0f;              // scale 16: keeps lo out of denorms
        _Float16 h = (_Float16)sv;
        float hf = (float)h;
        _Float16 l = (_Float16)(sv - hf);
        union { _Float16 f16; u16 u; } uh, ul;
        uh.f16 = h; ul.f16 = l;
        hs[j] = uh.u; ls[j] = ul.u;
    }
    uint4 H, Lo;
    H.x  = hs[0] | ((unsigned)hs[1] << 16); H.y  = hs[2] | ((unsigned)hs[3] << 16);
    H.z  = hs[4] | ((unsigned)hs[5] << 16); H.w  = hs[6] | ((unsigned)hs[7] << 16);
    Lo.x = ls[0] | ((unsigned)ls[1] << 16); Lo.y = ls[2] | ((unsigned)ls[3] << 16);
    Lo.z = ls[4] | ((unsigned)ls[5] << 16); Lo.w = ls[6] | ((unsigned)ls[7] << 16);
    *(uint4*)(dh + (size_t)c * 8) = H;
    *(uint4*)(dl + (size_t)c * 8) = Lo;
}

__global__ __launch_bounds__(256) void nn_prep(const float* __restrict__ x,
                                               const float* __restrict__ codes,
                                               u16* __restrict__ xh, u16* __restrict__ xl,
                                               u16* __restrict__ ch, u16* __restrict__ cl,
                                               float* __restrict__ c2) {
    int b = blockIdx.x;
    if (b < 2048) {
        conv_body(x, xh, xl, b * 256 + threadIdx.x);
    } else if (b < 6144) {
        conv_body(codes, ch, cl, (b - 2048) * 256 + threadIdx.x);
    } else {
        int w = threadIdx.x >> 6;
        int lane = threadIdx.x & 63;
        int c = (b - 6144) * 4 + w;
        const float* p = codes + (size_t)c * DDIM + lane * 8;
        float4 v0 = *(const float4*)p;
        float4 v1 = *(const float4*)(p + 4);
        float s = v0.x*v0.x + v0.y*v0.y + v0.z*v0.z + v0.w*v0.w
                + v1.x*v1.x + v1.y*v1.y + v1.z*v1.z + v1.w*v1.w;
        #pragma unroll
        for (int off = 32; off > 0; off >>= 1) s += __shfl_down(s, off);
        if (lane == 0) c2[c] = s;
    }
}

// ---------------- kernel 2: 32x32 fp16x3 MFMA GEMM + fused argmin -----------
// grid = 32 mtiles * 8 chunks, blockIdx.x = mtile*8 + chunk (chunk<->XCD).
// Block: 512 threads = 8 waves (wm=wave&3 row-quarter, wn=wave>>2 col-half);
// block tile 256 rows x 256 cols per nt (nt=0..7 over CHUNK=2048).
// Wave tile 64x128 = 2x4 tiles of 32x32. LDS: 2 x 64KB ping-pong
// [Ah 16K|Al 16K|Bh 16K|Bl 16K] + 4KB running-min table at 128K.
__global__ __launch_bounds__(512, 2) void nn_gemm(const u16* __restrict__ xh,
                                                  const u16* __restrict__ xl,
                                                  const u16* __restrict__ chh,
                                                  const u16* __restrict__ cll,
                                                  const float* __restrict__ c2,
                                                  float* __restrict__ pmin,
                                                  int* __restrict__ pid) {
    __shared__ __align__(16) char smem[139264];
    const int tid = threadIdx.x;
    const int lane = tid & 63;
    const int wave = tid >> 6;          // 0..7
    const int wm = wave & 3;            // 64-row quarter
    const int wn = wave >> 2;           // 128-col half
    const int mtile = blockIdx.x >> 3;  // 0..31
    const int chunk = blockIdx.x & 7;   // 0..7
    const int m0 = mtile * 256;
    char* tb = smem + 131072;           // 512 x int2 running (val,id) table

    // init running-min table (rows x wn-half); covered by it=0 top barrier
    if (tid < 512) {
        int2 e; e.x = __float_as_int(3.4e38f); e.y = 0;
        *(int2*)(tb + tid * 8) = e;
    }

    // wave-static staging role: plane = wave>>1 (0 Ah,1 Al,2 Bh,3 Bl),
    // tsub = wave&1 selects which 128-row/col subtile of the 256-tile.
    const int plane = wave >> 1;
    const int tsub  = wave & 1;
    const bool isA = (plane < 2);
    const u16* gbase;
    if (plane == 0)      gbase = xh  + ((size_t)(mtile * 2 + tsub) * 16) * 4096;
    else if (plane == 1) gbase = xl  + ((size_t)(mtile * 2 + tsub) * 16) * 4096;
    else if (plane == 2) gbase = chh + ((size_t)(chunk * 16 + tsub) * 16) * 4096;
    else                 gbase = cll + ((size_t)(chunk * 16 + tsub) * 16) * 4096;
    gbase += lane * 8;
    // LDS dst region for this wave: plane p at p*16KB, subtile at tsub*8KB
    const int ldsoff = wave * 8192;     // == plane*16384 + tsub*8192

    f32x16 acc[2][4];
    #pragma unroll
    for (int i = 0; i < 2; ++i)
        #pragma unroll
        for (int j = 0; j < 4; ++j) acc[i][j] = (f32x16)0.0f;

    // stage iteration it2 = nt*16 + kit into buffer (it2&1)
    auto stage = [&](int it2) {
        int kit2 = it2 & 15, nt2 = it2 >> 4;
        size_t off = (size_t)(isA ? kit2 : nt2 * 32 + kit2) * 4096;
        const u16* src = gbase + off;
        char* dst = smem + (size_t)(it2 & 1) * 65536 + ldsoff;
        #pragma unroll
        for (int s = 0; s < 8; ++s)
            __builtin_amdgcn_global_load_lds(
                (const __attribute__((address_space(1))) void*)(src + s * 512),
                (__attribute__((address_space(3))) void*)(dst + s * 1024),
                16, 0, 0);
    };

    stage(0);
    for (int it = 0; it < 128; ++it) {
        if (it < 127) {
            stage(it + 1);
            // wait only for LAST iteration's 8 loads; this iteration's 8
            // stay in flight across the barrier (counted vmcnt).
            asm volatile("s_waitcnt vmcnt(8)\n\ts_barrier" ::: "memory");
        } else {
            asm volatile("s_waitcnt vmcnt(0)\n\ts_barrier" ::: "memory");
        }

        const char* cur = smem + (size_t)(it & 1) * 65536;

        #pragma unroll
        for (int ks = 0; ks < 2; ++ks) {
            half8 ah[2], al[2];
            #pragma unroll
            for (int i = 0; i < 2; ++i) {
                int gg = wm * 2 + i;            // A 32-row group (0..7)
                int aoff = (gg >> 2) * 8192 + ((gg & 3) * 2 + ks) * 1024 + lane * 16;
                ah[i] = *(const half8*)(cur +         aoff);
                al[i] = *(const half8*)(cur + 16384 + aoff);
            }
            #pragma unroll
            for (int j = 0; j < 4; ++j) {
                int cg = wn * 4 + j;            // B 32-col group (0..7)
                int boff = 32768 + (cg >> 2) * 8192 + ((cg & 3) * 2 + ks) * 1024 + lane * 16;
                half8 bh = *(const half8*)(cur +         boff);
                half8 bl = *(const half8*)(cur + 16384 + boff);
                #pragma unroll
                for (int i = 0; i < 2; ++i) {
                    acc[i][j] = __builtin_amdgcn_mfma_f32_32x32x16_f16(ah[i], bh, acc[i][j], 0, 0, 0);
                    acc[i][j] = __builtin_amdgcn_mfma_f32_32x32x16_f16(ah[i], bl, acc[i][j], 0, 0, 0);
                    acc[i][j] = __builtin_amdgcn_mfma_f32_32x32x16_f16(al[i], bh, acc[i][j], 0, 0, 0);
                }
            }
        }

        if ((it & 15) == 15) {
            // epilogue for nt: score = ||c||^2 - acc/128 (acc = 256 * x.c).
            // slot s = i*16 + r -> local row wm*64 + (s>>4)*32 + (s&3)
            //   + 8*((s>>2)&3) + 4*(lane>>5); col of candidate = j*32+(lane&31).
            int nt = it >> 4;
            float mvs[32]; int mis[32];
            #pragma unroll
            for (int s = 0; s < 32; ++s) { mvs[s] = 3.4e38f; mis[s] = 0; }
            #pragma unroll
            for (int j = 0; j < 4; ++j) {
                int col = j * 32 + (lane & 31);         // 0..127 within wn-half
                float cv = c2[chunk * CHUNK + nt * 256 + wn * 128 + col];
                #pragma unroll
                for (int i = 0; i < 2; ++i)
                    #pragma unroll
                    for (int r = 0; r < 16; ++r) {
                        float sc = fmaf(acc[i][j][r], -0.0078125f, cv);
                        int slot = i * 16 + r;
                        // cols ascend with j -> '<' keeps lowest id
                        if (sc < mvs[slot]) { mvs[slot] = sc; mis[slot] = col; }
                    }
            }
            // reduce across the 32 col-lanes of each half (bit5 preserved)
            #pragma unroll
            for (int off = 1; off < 32; off <<= 1) {
                #pragma unroll
                for (int s = 0; s < 32; ++s) {
                    float ov = __shfl_xor(mvs[s], off);
                    int   oi = __shfl_xor(mis[s], off);
                    if (ov < mvs[s] || (ov == mvs[s] && oi < mis[s])) { mvs[s] = ov; mis[s] = oi; }
                }
            }
            // single-owner running update: wave (wm,wn) owns rows wm*64..+63
            // in table column wn; lanes 0 and 32 cover disjoint row sets.
            if ((lane & 31) == 0) {
                #pragma unroll
                for (int s = 0; s < 32; ++s) {
                    int row = wm * 64 + (s >> 4) * 32 + (s & 3) + ((s >> 2) & 3) * 8 + (lane >> 5) * 4;
                    int2* e = (int2*)(tb + (wn * 256 + row) * 8);
                    float bv = __int_as_float(e->x);
                    if (mvs[s] < bv) {  // nt ascends -> strict '<' keeps first id
                        int2 w;
                        w.x = __float_as_int(mvs[s]);
                        w.y = chunk * CHUNK + nt * 256 + wn * 128 + mis[s];
                        *e = w;
                    }
                }
            }
            #pragma unroll
            for (int i = 0; i < 2; ++i)
                #pragma unroll
                for (int j = 0; j < 4; ++j) acc[i][j] = (f32x16)0.0f;
        }
        // release barrier: all waves done reading `cur` before it is
        // re-staged at the top of the next iteration.
        asm volatile("s_barrier" ::: "memory");
    }

    __syncthreads();
    if (tid < 256) {
        int2 e0 = *(const int2*)(tb + tid * 8);
        int2 e1 = *(const int2*)(tb + (256 + tid) * 8);
        float v0 = __int_as_float(e0.x), v1 = __int_as_float(e1.x);
        float bv = v0; int bi = e0.y;
        if (v1 < bv || (v1 == bv && e1.y < bi)) { bv = v1; bi = e1.y; }
        pmin[(size_t)(m0 + tid) * NCHUNK + chunk] = bv;
        pid [(size_t)(m0 + tid) * NCHUNK + chunk] = bi;
    }
}

// ---------------- kernel 3: finalize (one wave per token) -------------------
__global__ __launch_bounds__(256) void nn_fin(const float* __restrict__ x,
                                              const float* __restrict__ pmin,
                                              const int* __restrict__ pid,
                                              int* __restrict__ out) {
    int w = threadIdx.x >> 6;
    int lane = threadIdx.x & 63;
    int t = blockIdx.x * 4 + w;
    const float* p = x + (size_t)t * DDIM + lane * 8;
    float4 v0 = *(const float4*)p;
    float4 v1 = *(const float4*)(p + 4);
    float s = v0.x*v0.x + v0.y*v0.y + v0.z*v0.z + v0.w*v0.w
            + v1.x*v1.x + v1.y*v1.y + v1.z*v1.z + v1.w*v1.w;
    #pragma unroll
    for (int off = 32; off > 0; off >>= 1) s += __shfl_down(s, off);
    if (lane == 0) {
        const float* pm = pmin + (size_t)t * NCHUNK;
        const int*   pi = pid  + (size_t)t * NCHUNK;
        float bv = pm[0]; int bi = pi[0];
        #pragma unroll
        for (int c = 1; c < NCHUNK; ++c) {
            float v = pm[c]; int id = pi[c];
            if (v < bv || (v == bv && id < bi)) { bv = v; bi = id; }
        }
        float mind = s + bv;   // ||x||^2 + min(||c||^2 - 2 x.c)
        out[t] = (mind <= DIST_THR) ? bi : -1;
    }
}

extern "C" void kernel_launch(void* const* d_in, const int* in_sizes, int n_in,
                              void* d_out, int out_size, void* d_ws, size_t ws_size,
                              hipStream_t stream) {
    const float* x     = (const float*)d_in[0];
    const float* codes = (const float*)d_in[1];
    int* out = (int*)d_out;

    // workspace layout (bytes):
    //  xh 8MB | xl 8MB | ch 16MB | cl 16MB | c2 64KB | pmin 256KB | pid 256KB
    char* ws = (char*)d_ws;
    u16*   xh   = (u16*)(ws);
    u16*   xl   = (u16*)(ws + 8388608);
    u16*   chh  = (u16*)(ws + 16777216);
    u16*   cll  = (u16*)(ws + 33554432);
    float* c2   = (float*)(ws + 50331648);
    float* pmin = (float*)(ws + 50397184);
    int*   pid  = (int*)  (ws + 50659328);

    nn_prep<<<10240, 256, 0, stream>>>(x, codes, xh, xl, chh, cll, c2);
    nn_gemm<<<32 * NCHUNK, 512, 0, stream>>>(xh, xl, chh, cll, c2, pmin, pid);
    nn_fin<<<NTOK / 4, 256, 0, stream>>>(x, pmin, pid, out);
}